// Round 13
// baseline (151.870 us; speedup 1.0000x reference)
//
#include <hip/hip_runtime.h>
#include <math.h>

#define D_IN  512
#define D_HID 64
#define D_OUT 40
#define CAP   64   // per-node edge capacity; deg ~ Poisson(16), max<<64

typedef __attribute__((ext_vector_type(8))) short bf16x8;
typedef __attribute__((ext_vector_type(4))) float f32x4;

static __device__ __forceinline__ unsigned short f2bf(float f) {
    unsigned u = __float_as_uint(f);
    return (unsigned short)((u + 0x7FFF + ((u >> 16) & 1)) >> 16);  // RNE
}
static __device__ __forceinline__ float bf2f(unsigned short h) {
    return __uint_as_float(((unsigned)h) << 16);
}

// ===========================================================================
// prep_all: zero cursor (N) | W1 -> w1T bf16 transposed | W2 -> w2T bf16
// ===========================================================================
__global__ __launch_bounds__(256)
void prep_all(int* __restrict__ cursor, const float* __restrict__ W1,
              unsigned short* __restrict__ w1T, const float* __restrict__ W2,
              unsigned short* __restrict__ w2T, int N) {
    const int i = blockIdx.x * blockDim.x + threadIdx.x;
    if (i < N) cursor[i] = 0;
    const int j = i - N;
    if (j >= 0 && j < D_IN * D_HID) {          // j = k*64 + col
        const int k = j >> 6, col = j & 63;
        w1T[col * D_IN + k] = f2bf(W1[j]);
    }
    const int l = j - D_IN * D_HID;
    if (l >= 0 && l < 48 * D_HID) {            // l = col*64 + k
        const int col = l >> 6, k = l & 63;
        w2T[l] = (col < D_OUT) ? f2bf(W2[k * D_OUT + col]) : 0;
    }
}

// ===========================================================================
// Capacity-CSR scatter, XCD-local. Edge record: (src<<16) | bf16(w).
// cursor[n] ends as the node's edge count.
// ===========================================================================
__global__ __launch_bounds__(256)
void scatter_cap(const int* __restrict__ src, const int* __restrict__ dstA,
                 const float* __restrict__ wm, int* __restrict__ cursor,
                 unsigned* __restrict__ edges, int E, int N) {
    const int slice = (N + 7) >> 3;
    const int lo = (blockIdx.x & 7) * slice;
    const int hi = min(N, lo + slice);
    const int nChunk = gridDim.x >> 3;
    const int per = (E + nChunk - 1) / nChunk;
    const int beg = (blockIdx.x >> 3) * per;
    const int end = min(E, beg + per);
    for (int e = beg + threadIdx.x; e < end; e += blockDim.x) {
        const int d = dstA[e];
        if (d >= lo && d < hi) {
            const int pos = atomicAdd(&cursor[d], 1);
            if (pos < CAP)
                edges[(size_t)d * CAP + pos] =
                    ((unsigned)src[e] << 16) | (unsigned)f2bf(wm[e]);
        }
    }
}

// ===========================================================================
// GEMM1 (MFMA bf16): h1[N,64](bf16) = x[N,512] @ W1 + b1
// FULL W1 (64 KB bf16, swizzled) staged in LDS once -> the K=512 loop has
// ZERO barriers, so the compiler hoists the 32 independent per-lane x-loads
// (r12 post-mortem: 2 barriers/k-chunk left ~4 loads in flight -> 95 us
// latency-bound at VALUBusy 5.7%). A-fragments direct from global.
// ===========================================================================
__global__ __launch_bounds__(256)
void gemm1_mfma(const float* __restrict__ x, const unsigned short* __restrict__ w1T,
                const float* __restrict__ b1, unsigned short* __restrict__ h1, int N) {
    __shared__ unsigned char lds[65536];  // W1: 64 cols x 512 k bf16, swizzled
    const int t = threadIdx.x;
    const int lane = t & 63;
    const int wv = t >> 6;
    const int nodeBase = blockIdx.x * 64;
    const int fr = lane & 15;
    const int fc = lane >> 4;

    // stage all of W1: 4096 x 16B granules, 16 per thread
#pragma unroll
    for (int g = t; g < 4096; g += 256) {
        const int col = g >> 6, gs = g & 63;   // gs: k-granule (k = gs*8)
        const uint4 p = *reinterpret_cast<const uint4*>(w1T + (size_t)col * D_IN + gs * 8);
        *reinterpret_cast<uint4*>(lds + col * 1024 + ((gs * 16) ^ ((col & 7) << 4))) = p;
    }
    __syncthreads();  // the only barrier

    int gn = nodeBase + wv * 16 + fr; if (gn >= N) gn = N - 1;
    const float* xrow = x + (size_t)gn * D_IN + fc * 8;

    f32x4 acc[4];
#pragma unroll
    for (int cg = 0; cg < 4; ++cg) acc[cg] = (f32x4){0.f, 0.f, 0.f, 0.f};

#pragma unroll
    for (int k0 = 0; k0 < D_IN; k0 += 64) {
#pragma unroll
        for (int s = 0; s < 2; ++s) {
            const float4 a = *reinterpret_cast<const float4*>(xrow + k0 + s * 32);
            const float4 b = *reinterpret_cast<const float4*>(xrow + k0 + s * 32 + 4);
            uint4 p;
            p.x = (unsigned)f2bf(a.x) | ((unsigned)f2bf(a.y) << 16);
            p.y = (unsigned)f2bf(a.z) | ((unsigned)f2bf(a.w) << 16);
            p.z = (unsigned)f2bf(b.x) | ((unsigned)f2bf(b.y) << 16);
            p.w = (unsigned)f2bf(b.z) | ((unsigned)f2bf(b.w) << 16);
            const bf16x8 afrag = *reinterpret_cast<const bf16x8*>(&p);
            const int slot = s * 4 + fc;
#pragma unroll
            for (int cg = 0; cg < 4; ++cg) {
                const int brow = cg * 16 + fr;
                const bf16x8 bfrag = *reinterpret_cast<const bf16x8*>(
                    lds + brow * 1024 + k0 * 2 + ((slot << 4) ^ ((brow & 7) << 4)));
                acc[cg] = __builtin_amdgcn_mfma_f32_16x16x32_bf16(afrag, bfrag, acc[cg], 0, 0, 0);
            }
        }
    }

    const int rq = lane >> 4;
#pragma unroll
    for (int cg = 0; cg < 4; ++cg) {
        const int col = cg * 16 + fr;
        const float bb = b1[col];
#pragma unroll
        for (int r = 0; r < 4; ++r) {
            const int node = nodeBase + wv * 16 + rq * 4 + r;
            if (node < N)
                h1[(size_t)node * D_HID + col] = f2bf(acc[cg][r] + bb);
        }
    }
}

// ===========================================================================
// fatB: aggregation-1 (64ch, wave=node-row, lane=channel) fused with GEMM2.
// Block owns 64 nodes: 4 waves x 16 nodes (pipelined edge-record prefetch),
// relu'd bf16 acc written into the swizzled LDS A-tile, then MFMA vs w2T
// -> h2[N,40] directly. No agg1 global round-trip.
// ===========================================================================
__global__ __launch_bounds__(256)
void fatB(const unsigned short* __restrict__ h1, const unsigned* __restrict__ edges,
          const int* __restrict__ count, const unsigned short* __restrict__ w2T,
          const float* __restrict__ b2, unsigned short* __restrict__ h2, int N) {
    __shared__ unsigned char lds[8192 + 6144];  // A @0 (64x128B), B @8192 (48x128B)
    const int t = threadIdx.x;
    const int lane = t & 63;
    const int wv = t >> 6;
    const int nodeBase = blockIdx.x * 64;

    for (int g = t; g < 384; g += 256) {
        const int row = g >> 3, slot = g & 7;
        const uint4 p = *reinterpret_cast<const uint4*>(w2T + (size_t)row * D_HID + slot * 8);
        *reinterpret_cast<uint4*>(lds + 8192 + row * 128 + ((slot << 4) ^ ((row & 7) << 4))) = p;
    }

    {
        const int n0 = nodeBase + wv * 16;
        unsigned er = edges[(size_t)min(n0, N - 1) * CAP + lane];
        int cnt = (n0 < N) ? min(count[n0], CAP) : 0;
#pragma unroll 1
        for (int i = 0; i < 16; ++i) {
            const int r = wv * 16 + i;
            unsigned erN = 0; int cntN = 0;
            if (i < 15) {
                const int nn = nodeBase + r + 1;
                erN = edges[(size_t)min(nn, N - 1) * CAP + lane];
                cntN = (nn < N) ? min(count[nn], CAP) : 0;
            }
            float acc = 0.f;
            int j = 0;
            for (; j + 8 <= cnt; j += 8) {
                unsigned p[8];
#pragma unroll
                for (int u = 0; u < 8; ++u) p[u] = (unsigned)__shfl((int)er, j + u);
                float v[8];
#pragma unroll
                for (int u = 0; u < 8; ++u)
                    v[u] = bf2f(h1[(size_t)(p[u] >> 16) * D_HID + lane]);
#pragma unroll
                for (int u = 0; u < 8; ++u)
                    acc += bf2f((unsigned short)(p[u] & 0xffff)) * v[u];
            }
            for (; j < cnt; ++j) {
                const unsigned p0 = (unsigned)__shfl((int)er, j);
                acc += bf2f((unsigned short)(p0 & 0xffff)) *
                       bf2f(h1[(size_t)(p0 >> 16) * D_HID + lane]);
            }
            const unsigned short hv = f2bf(fmaxf(acc, 0.f));
            *reinterpret_cast<unsigned short*>(
                lds + r * 128 + (((lane >> 3) << 4) ^ ((r & 7) << 4)) + (lane & 7) * 2) = hv;
            er = erN; cnt = cntN;
        }
    }
    __syncthreads();

    f32x4 acc2[3];
#pragma unroll
    for (int cg = 0; cg < 3; ++cg) acc2[cg] = (f32x4){0.f, 0.f, 0.f, 0.f};

    const int fr = lane & 15;
    const int fc = lane >> 4;
#pragma unroll
    for (int s = 0; s < 2; ++s) {
        const int slot = s * 4 + fc;
        const int arow = wv * 16 + fr;
        const bf16x8 afrag = *reinterpret_cast<const bf16x8*>(
            lds + arow * 128 + ((slot << 4) ^ ((arow & 7) << 4)));
#pragma unroll
        for (int cg = 0; cg < 3; ++cg) {
            const int brow = cg * 16 + fr;
            const bf16x8 bfrag = *reinterpret_cast<const bf16x8*>(
                lds + 8192 + brow * 128 + ((slot << 4) ^ ((brow & 7) << 4)));
            acc2[cg] = __builtin_amdgcn_mfma_f32_16x16x32_bf16(afrag, bfrag, acc2[cg], 0, 0, 0);
        }
    }

    const int rq = lane >> 4;
#pragma unroll
    for (int cg = 0; cg < 3; ++cg) {
        const int col = cg * 16 + fr;
        if (col < D_OUT) {
            const float bb = b2[col];
#pragma unroll
            for (int r = 0; r < 4; ++r) {
                const int node = nodeBase + wv * 16 + rq * 4 + r;
                if (node < N)
                    h2[(size_t)node * D_OUT + col] = f2bf(acc2[cg][r] + bb);
            }
        }
    }
}

// ===========================================================================
// Aggregation 2 (40 ch) + log_softmax. Capacity-CSR, 8-deep gathers.
// ===========================================================================
__global__ __launch_bounds__(256)
void agg40_lsm(const unsigned short* __restrict__ h2, const unsigned* __restrict__ edges,
               const int* __restrict__ count, float* __restrict__ out, int N) {
    const int lane = threadIdx.x & 63;
    const int col  = (lane < D_OUT) ? lane : 0;  // clamped gather, no branch
    const int n = (blockIdx.x * blockDim.x + threadIdx.x) >> 6;
    if (n >= N) return;
    const unsigned er = edges[(size_t)n * CAP + lane];
    const int cnt = min(count[n], CAP);
    float acc = 0.f;
    int j = 0;
    for (; j + 8 <= cnt; j += 8) {
        unsigned p[8];
#pragma unroll
        for (int u = 0; u < 8; ++u) p[u] = (unsigned)__shfl((int)er, j + u);
        float v[8];
#pragma unroll
        for (int u = 0; u < 8; ++u) v[u] = bf2f(h2[(size_t)(p[u] >> 16) * D_OUT + col]);
#pragma unroll
        for (int u = 0; u < 8; ++u)
            acc += bf2f((unsigned short)(p[u] & 0xffff)) * v[u];
    }
    for (; j < cnt; ++j) {
        const unsigned p0 = (unsigned)__shfl((int)er, j);
        acc += bf2f((unsigned short)(p0 & 0xffff)) *
               bf2f(h2[(size_t)(p0 >> 16) * D_OUT + col]);
    }
    const float v = (lane < D_OUT) ? acc : -INFINITY;
    float m = v;
#pragma unroll
    for (int o = 32; o > 0; o >>= 1) m = fmaxf(m, __shfl_xor(m, o, 64));
    float s = (lane < D_OUT) ? __expf(v - m) : 0.f;
#pragma unroll
    for (int o = 32; o > 0; o >>= 1) s += __shfl_xor(s, o, 64);
    if (lane < D_OUT) out[(size_t)n * D_OUT + lane] = v - m - __logf(s);
}

// ===========================================================================
extern "C" void kernel_launch(void* const* d_in, const int* in_sizes, int n_in,
                              void* d_out, int out_size, void* d_ws, size_t ws_size,
                              hipStream_t stream) {
    const float* x   = (const float*)d_in[0];
    const int*   ei  = (const int*)d_in[1];
    const float* wm  = (const float*)d_in[2];
    const float* W1  = (const float*)d_in[3];
    const float* b1  = (const float*)d_in[4];
    const float* W2  = (const float*)d_in[5];
    const float* b2  = (const float*)d_in[6];

    const int N = in_sizes[0] / D_IN;   // 50000
    const int E = in_sizes[2];          // 800000
    const int* srcIdx = ei;
    const int* dstIdx = ei + E;

    // workspace layout (16B-aligned blocks)
    unsigned short* w1T  = (unsigned short*)d_ws;                   // 64 KiB
    unsigned short* h1bf = w1T + (size_t)D_HID * D_IN;              // N*64 bf16
    unsigned short* h2bf = h1bf + (size_t)N * D_HID;                // N*40 bf16 (own buf)
    unsigned* edges      = (unsigned*)(h2bf + (size_t)N * D_HID);   // N*CAP u32
    int*   cursor        = (int*)(edges + (size_t)N * CAP);         // N (= counts)
    unsigned short* w2T  = (unsigned short*)(cursor + N);           // 48*64 bf16
    float* out           = (float*)d_out;

    const int g1Blocks = (N + 63) / 64;          // 782
    const int prepWork = N + D_IN * D_HID + 48 * D_HID;

    prep_all<<<(prepWork + 255) / 256, 256, 0, stream>>>(cursor, W1, w1T, W2, w2T, N);
    gemm1_mfma<<<g1Blocks, 256, 0, stream>>>(x, w1T, b1, h1bf, N);
    scatter_cap<<<2048, 256, 0, stream>>>(srcIdx, dstIdx, wm, cursor, edges, E, N);
    fatB<<<g1Blocks, 256, 0, stream>>>(h1bf, edges, cursor, w2T, b2, h2bf, N);
    agg40_lsm<<<(N * 64 + 255) / 256, 256, 0, stream>>>(h2bf, edges, cursor, out, N);
}

// Round 14
// 131.940 us; speedup vs baseline: 1.1510x; 1.1510x over previous
//
#include <hip/hip_runtime.h>
#include <math.h>

#define D_IN  512
#define D_HID 64
#define D_OUT 40
#define CAP   64   // per-node edge capacity; deg ~ Poisson(16), max<<64

typedef __attribute__((ext_vector_type(8))) short bf16x8;
typedef __attribute__((ext_vector_type(4))) float f32x4;

static __device__ __forceinline__ unsigned short f2bf(float f) {
    unsigned u = __float_as_uint(f);
    return (unsigned short)((u + 0x7FFF + ((u >> 16) & 1)) >> 16);  // RNE
}
static __device__ __forceinline__ float bf2f(unsigned short h) {
    return __uint_as_float(((unsigned)h) << 16);
}

// ===========================================================================
// prep_all: zero cursor (N) | W1 -> w1T bf16 transposed | W2 -> w2T bf16
// ===========================================================================
__global__ __launch_bounds__(256)
void prep_all(int* __restrict__ cursor, const float* __restrict__ W1,
              unsigned short* __restrict__ w1T, const float* __restrict__ W2,
              unsigned short* __restrict__ w2T, int N) {
    const int i = blockIdx.x * blockDim.x + threadIdx.x;
    if (i < N) cursor[i] = 0;
    const int j = i - N;
    if (j >= 0 && j < D_IN * D_HID) {          // j = k*64 + col
        const int k = j >> 6, col = j & 63;
        w1T[col * D_IN + k] = f2bf(W1[j]);
    }
    const int l = j - D_IN * D_HID;
    if (l >= 0 && l < 48 * D_HID) {            // l = col*64 + k
        const int col = l >> 6, k = l & 63;
        w2T[l] = (col < D_OUT) ? f2bf(W2[k * D_OUT + col]) : 0;
    }
}

// ===========================================================================
// Capacity-CSR scatter, XCD-local. Edge record: (src<<16) | bf16(w).
// cursor[n] ends as the node's edge count.
// ===========================================================================
__global__ __launch_bounds__(256)
void scatter_cap(const int* __restrict__ src, const int* __restrict__ dstA,
                 const float* __restrict__ wm, int* __restrict__ cursor,
                 unsigned* __restrict__ edges, int E, int N) {
    const int slice = (N + 7) >> 3;
    const int lo = (blockIdx.x & 7) * slice;
    const int hi = min(N, lo + slice);
    const int nChunk = gridDim.x >> 3;
    const int per = (E + nChunk - 1) / nChunk;
    const int beg = (blockIdx.x >> 3) * per;
    const int end = min(E, beg + per);
    for (int e = beg + threadIdx.x; e < end; e += blockDim.x) {
        const int d = dstA[e];
        if (d >= lo && d < hi) {
            const int pos = atomicAdd(&cursor[d], 1);
            if (pos < CAP)
                edges[(size_t)d * CAP + pos] =
                    ((unsigned)src[e] << 16) | (unsigned)f2bf(wm[e]);
        }
    }
}

// ===========================================================================
// GEMM1 (MFMA bf16): h1[N,64](bf16) = x[N,512] @ W1 + b1
// r4-r10 verified structure: BOTH operands LDS-staged per 64-k chunk via
// coalesced full-wave uint4 loads (high MLP during staging), 16 KB LDS,
// 2 barriers/chunk. r11's direct-global-A variant measured 70-95 us
// (latency-bound, r12 fatA); this one ran <=~30 us in r4-r10.
// ===========================================================================
__global__ __launch_bounds__(256)
void gemm1_mfma(const float* __restrict__ x, const unsigned short* __restrict__ w1T,
                const float* __restrict__ b1, unsigned short* __restrict__ h1, int N) {
    __shared__ unsigned char lds[16384];  // xs @0, ws @8192
    const int t = threadIdx.x;
    const int lane = t & 63;
    const int wv = t >> 6;
    const int nodeBase = blockIdx.x * 64;

    f32x4 acc[4];
#pragma unroll
    for (int cg = 0; cg < 4; ++cg) acc[cg] = (f32x4){0.f, 0.f, 0.f, 0.f};

    for (int k0 = 0; k0 < D_IN; k0 += 64) {
#pragma unroll
        for (int hh = 0; hh < 2; ++hh) {
            const int g = t + hh * 256;          // 0..511
            const int row = g >> 3, slot = g & 7;
            int gn = nodeBase + row; if (gn >= N) gn = N - 1;
            const float* sp = x + (size_t)gn * D_IN + k0 + slot * 8;
            const float4 a = *reinterpret_cast<const float4*>(sp);
            const float4 b = *reinterpret_cast<const float4*>(sp + 4);
            uint4 p;
            p.x = (unsigned)f2bf(a.x) | ((unsigned)f2bf(a.y) << 16);
            p.y = (unsigned)f2bf(a.z) | ((unsigned)f2bf(a.w) << 16);
            p.z = (unsigned)f2bf(b.x) | ((unsigned)f2bf(b.y) << 16);
            p.w = (unsigned)f2bf(b.z) | ((unsigned)f2bf(b.w) << 16);
            *reinterpret_cast<uint4*>(lds + row * 128 + ((slot << 4) ^ ((row & 7) << 4))) = p;
        }
#pragma unroll
        for (int hh = 0; hh < 2; ++hh) {
            const int g = t + hh * 256;
            const int col = g >> 3, slot = g & 7;
            const uint4 p = *reinterpret_cast<const uint4*>(w1T + (size_t)col * D_IN + k0 + slot * 8);
            *reinterpret_cast<uint4*>(lds + 8192 + col * 128 + ((slot << 4) ^ ((col & 7) << 4))) = p;
        }
        __syncthreads();

        const int fr = lane & 15;
        const int fc = lane >> 4;
#pragma unroll
        for (int s = 0; s < 2; ++s) {
            const int slot = s * 4 + fc;
            const int arow = wv * 16 + fr;
            const bf16x8 afrag = *reinterpret_cast<const bf16x8*>(
                lds + arow * 128 + ((slot << 4) ^ ((arow & 7) << 4)));
#pragma unroll
            for (int cg = 0; cg < 4; ++cg) {
                const int brow = cg * 16 + fr;
                const bf16x8 bfrag = *reinterpret_cast<const bf16x8*>(
                    lds + 8192 + brow * 128 + ((slot << 4) ^ ((brow & 7) << 4)));
                acc[cg] = __builtin_amdgcn_mfma_f32_16x16x32_bf16(afrag, bfrag, acc[cg], 0, 0, 0);
            }
        }
        __syncthreads();
    }

    const int fr = lane & 15;
    const int rq = lane >> 4;
#pragma unroll
    for (int cg = 0; cg < 4; ++cg) {
        const int col = cg * 16 + fr;
        const float bb = b1[col];
#pragma unroll
        for (int r = 0; r < 4; ++r) {
            const int node = nodeBase + wv * 16 + rq * 4 + r;
            if (node < N)
                h1[(size_t)node * D_HID + col] = f2bf(acc[cg][r] + bb);
        }
    }
}

// ===========================================================================
// Aggregation 1 (64 ch): wave/node, lane=channel, capacity-CSR (single
// chunk, coalesced edge load). 8 independent gathers in flight.
// Fused relu + bf16 store. High-occupancy standalone (r13 fatB fusion
// collapsed occupancy to 27% -> 56.8 us; this ran ~20 us).
// ===========================================================================
__global__ __launch_bounds__(256)
void agg_hid(const unsigned short* __restrict__ h, const unsigned* __restrict__ edges,
             const int* __restrict__ count, unsigned short* __restrict__ agg1, int N) {
    const int lane = threadIdx.x & 63;
    const int n = (blockIdx.x * blockDim.x + threadIdx.x) >> 6;
    if (n >= N) return;
    const unsigned er = edges[(size_t)n * CAP + lane];
    const int cnt = min(count[n], CAP);
    float acc = 0.f;
    int j = 0;
    for (; j + 8 <= cnt; j += 8) {
        unsigned p[8];
#pragma unroll
        for (int u = 0; u < 8; ++u) p[u] = (unsigned)__shfl((int)er, j + u);
        float v[8];
#pragma unroll
        for (int u = 0; u < 8; ++u) v[u] = bf2f(h[(size_t)(p[u] >> 16) * D_HID + lane]);
#pragma unroll
        for (int u = 0; u < 8; ++u)
            acc += bf2f((unsigned short)(p[u] & 0xffff)) * v[u];
    }
    for (; j < cnt; ++j) {
        const unsigned p0 = (unsigned)__shfl((int)er, j);
        acc += bf2f((unsigned short)(p0 & 0xffff)) *
               bf2f(h[(size_t)(p0 >> 16) * D_HID + lane]);
    }
    agg1[(size_t)n * D_HID + lane] = f2bf(fmaxf(acc, 0.f));  // fused relu
}

// ===========================================================================
// GEMM2 (MFMA bf16): h2[N,40](bf16) = agg1relu[N,64] @ W2 + b2
// ===========================================================================
__global__ __launch_bounds__(256)
void gemm2_mfma(const unsigned short* __restrict__ agg1,
                const unsigned short* __restrict__ w2T,
                const float* __restrict__ b2, unsigned short* __restrict__ h2, int N) {
    __shared__ unsigned char lds[8192 + 6144];  // A @0 (64x128B), B @8192 (48x128B)
    const int t = threadIdx.x;
    const int lane = t & 63;
    const int wv = t >> 6;
    const int nodeBase = blockIdx.x * 64;

#pragma unroll
    for (int hh = 0; hh < 2; ++hh) {
        const int g = t + hh * 256;
        const int row = g >> 3, slot = g & 7;
        int gn = nodeBase + row; if (gn >= N) gn = N - 1;
        const uint4 p = *reinterpret_cast<const uint4*>(agg1 + (size_t)gn * D_HID + slot * 8);
        *reinterpret_cast<uint4*>(lds + row * 128 + ((slot << 4) ^ ((row & 7) << 4))) = p;
    }
    for (int g = t; g < 384; g += 256) {
        const int row = g >> 3, slot = g & 7;
        const uint4 p = *reinterpret_cast<const uint4*>(w2T + (size_t)row * D_HID + slot * 8);
        *reinterpret_cast<uint4*>(lds + 8192 + row * 128 + ((slot << 4) ^ ((row & 7) << 4))) = p;
    }
    __syncthreads();

    f32x4 acc[3];
#pragma unroll
    for (int cg = 0; cg < 3; ++cg) acc[cg] = (f32x4){0.f, 0.f, 0.f, 0.f};

    const int fr = lane & 15;
    const int fc = lane >> 4;
#pragma unroll
    for (int s = 0; s < 2; ++s) {
        const int slot = s * 4 + fc;
        const int arow = wv * 16 + fr;
        const bf16x8 afrag = *reinterpret_cast<const bf16x8*>(
            lds + arow * 128 + ((slot << 4) ^ ((arow & 7) << 4)));
#pragma unroll
        for (int cg = 0; cg < 3; ++cg) {
            const int brow = cg * 16 + fr;
            const bf16x8 bfrag = *reinterpret_cast<const bf16x8*>(
                lds + 8192 + brow * 128 + ((slot << 4) ^ ((brow & 7) << 4)));
            acc[cg] = __builtin_amdgcn_mfma_f32_16x16x32_bf16(afrag, bfrag, acc[cg], 0, 0, 0);
        }
    }

    const int rq = lane >> 4;
#pragma unroll
    for (int cg = 0; cg < 3; ++cg) {
        const int col = cg * 16 + fr;
        if (col < D_OUT) {
            const float bb = b2[col];
#pragma unroll
            for (int r = 0; r < 4; ++r) {
                const int node = nodeBase + wv * 16 + rq * 4 + r;
                if (node < N)
                    h2[(size_t)node * D_OUT + col] = f2bf(acc[cg][r] + bb);
            }
        }
    }
}

// ===========================================================================
// Aggregation 2 (40 ch) + log_softmax. Capacity-CSR, 8-deep gathers.
// ===========================================================================
__global__ __launch_bounds__(256)
void agg40_lsm(const unsigned short* __restrict__ h2, const unsigned* __restrict__ edges,
               const int* __restrict__ count, float* __restrict__ out, int N) {
    const int lane = threadIdx.x & 63;
    const int col  = (lane < D_OUT) ? lane : 0;  // clamped gather, no branch
    const int n = (blockIdx.x * blockDim.x + threadIdx.x) >> 6;
    if (n >= N) return;
    const unsigned er = edges[(size_t)n * CAP + lane];
    const int cnt = min(count[n], CAP);
    float acc = 0.f;
    int j = 0;
    for (; j + 8 <= cnt; j += 8) {
        unsigned p[8];
#pragma unroll
        for (int u = 0; u < 8; ++u) p[u] = (unsigned)__shfl((int)er, j + u);
        float v[8];
#pragma unroll
        for (int u = 0; u < 8; ++u) v[u] = bf2f(h2[(size_t)(p[u] >> 16) * D_OUT + col]);
#pragma unroll
        for (int u = 0; u < 8; ++u)
            acc += bf2f((unsigned short)(p[u] & 0xffff)) * v[u];
    }
    for (; j < cnt; ++j) {
        const unsigned p0 = (unsigned)__shfl((int)er, j);
        acc += bf2f((unsigned short)(p0 & 0xffff)) *
               bf2f(h2[(size_t)(p0 >> 16) * D_OUT + col]);
    }
    const float v = (lane < D_OUT) ? acc : -INFINITY;
    float m = v;
#pragma unroll
    for (int o = 32; o > 0; o >>= 1) m = fmaxf(m, __shfl_xor(m, o, 64));
    float s = (lane < D_OUT) ? __expf(v - m) : 0.f;
#pragma unroll
    for (int o = 32; o > 0; o >>= 1) s += __shfl_xor(s, o, 64);
    if (lane < D_OUT) out[(size_t)n * D_OUT + lane] = v - m - __logf(s);
}

// ===========================================================================
extern "C" void kernel_launch(void* const* d_in, const int* in_sizes, int n_in,
                              void* d_out, int out_size, void* d_ws, size_t ws_size,
                              hipStream_t stream) {
    const float* x   = (const float*)d_in[0];
    const int*   ei  = (const int*)d_in[1];
    const float* wm  = (const float*)d_in[2];
    const float* W1  = (const float*)d_in[3];
    const float* b1  = (const float*)d_in[4];
    const float* W2  = (const float*)d_in[5];
    const float* b2  = (const float*)d_in[6];

    const int N = in_sizes[0] / D_IN;   // 50000
    const int E = in_sizes[2];          // 800000
    const int* srcIdx = ei;
    const int* dstIdx = ei + E;

    // workspace layout (16B-aligned blocks)
    unsigned short* w1T    = (unsigned short*)d_ws;                   // 64 KiB
    unsigned short* h1bf   = w1T + (size_t)D_HID * D_IN;              // N*64 bf16
    unsigned short* agg1bf = h1bf + (size_t)N * D_HID;                // N*64 bf16 (relu'd)
    unsigned* edges        = (unsigned*)(agg1bf + (size_t)N * D_HID); // N*CAP u32
    int*   cursor          = (int*)(edges + (size_t)N * CAP);         // N (= counts)
    unsigned short* w2T    = (unsigned short*)(cursor + N);           // 48*64 bf16
    unsigned short* h2bf   = h1bf;                                    // reuse (h1 dead after agg_hid)
    float* out             = (float*)d_out;

    const int g1Blocks = (N + 63) / 64;          // 782
    const int prepWork = N + D_IN * D_HID + 48 * D_HID;

    prep_all<<<(prepWork + 255) / 256, 256, 0, stream>>>(cursor, W1, w1T, W2, w2T, N);
    scatter_cap<<<2048, 256, 0, stream>>>(srcIdx, dstIdx, wm, cursor, edges, E, N);
    gemm1_mfma<<<g1Blocks, 256, 0, stream>>>(x, w1T, b1, h1bf, N);
    agg_hid<<<(N * 64 + 255) / 256, 256, 0, stream>>>(h1bf, edges, cursor, agg1bf, N);
    gemm2_mfma<<<g1Blocks, 256, 0, stream>>>(agg1bf, w2T, b2, h2bf, N);
    agg40_lsm<<<(N * 64 + 255) / 256, 256, 0, stream>>>(h2bf, edges, cursor, out, N);
}

// Round 15
// 116.436 us; speedup vs baseline: 1.3043x; 1.1332x over previous
//
#include <hip/hip_runtime.h>
#include <math.h>

#define D_IN  512
#define D_HID 64
#define D_OUT 40
#define CAP   64   // per-node edge capacity; deg ~ Poisson(16), max<<64

typedef __attribute__((ext_vector_type(8))) short bf16x8;
typedef __attribute__((ext_vector_type(4))) float f32x4;

static __device__ __forceinline__ unsigned short f2bf(float f) {
    unsigned u = __float_as_uint(f);
    return (unsigned short)((u + 0x7FFF + ((u >> 16) & 1)) >> 16);  // RNE
}
static __device__ __forceinline__ float bf2f(unsigned short h) {
    return __uint_as_float(((unsigned)h) << 16);
}

// ===========================================================================
// prep_all: zero cursor (N) | W1 -> w1T bf16 transposed | W2 -> w2T bf16
// ===========================================================================
__global__ __launch_bounds__(256)
void prep_all(int* __restrict__ cursor, const float* __restrict__ W1,
              unsigned short* __restrict__ w1T, const float* __restrict__ W2,
              unsigned short* __restrict__ w2T, int N) {
    const int i = blockIdx.x * blockDim.x + threadIdx.x;
    if (i < N) cursor[i] = 0;
    const int j = i - N;
    if (j >= 0 && j < D_IN * D_HID) {          // j = k*64 + col
        const int k = j >> 6, col = j & 63;
        w1T[col * D_IN + k] = f2bf(W1[j]);
    }
    const int l = j - D_IN * D_HID;
    if (l >= 0 && l < 48 * D_HID) {            // l = col*64 + k
        const int col = l >> 6, k = l & 63;
        w2T[l] = (col < D_OUT) ? f2bf(W2[k * D_OUT + col]) : 0;
    }
}

// ===========================================================================
// fat1: blocks [0, sBlocks) = capacity-CSR scatter (XCD-local, dispatches
// FIRST so it overlaps); blocks [sBlocks, ...) = GEMM1 MFMA tiles.
// Both roles depend only on prep. 16 KB LDS -> 8 blocks/CU, whole grid
// (1024+782) nearly co-resident => scatter hides under gemm1.
// (r12's fatA failed because scatter queued AFTER gemm1 blocks and its
// gemm1 was the latency-bound direct-global variant.)
// ===========================================================================
__global__ __launch_bounds__(256)
void fat1(const float* __restrict__ x, const unsigned short* __restrict__ w1T,
          const float* __restrict__ b1, unsigned short* __restrict__ h1,
          const int* __restrict__ src, const int* __restrict__ dstA,
          const float* __restrict__ wm, int* __restrict__ cursor,
          unsigned* __restrict__ edges, int E, int N, int sBlocks) {
    __shared__ unsigned char lds[16384];  // gemm1 role: xs @0, ws @8192
    const int t = threadIdx.x;

    if ((int)blockIdx.x < sBlocks) {
        // ---------------- scatter: capacity-CSR, XCD-local ----------------
        const int slice = (N + 7) >> 3;
        const int lo = (blockIdx.x & 7) * slice;
        const int hi = min(N, lo + slice);
        const int nChunk = sBlocks >> 3;
        const int per = (E + nChunk - 1) / nChunk;
        const int beg = ((int)blockIdx.x >> 3) * per;
        const int end = min(E, beg + per);
        for (int e = beg + t; e < end; e += 256) {
            const int d = dstA[e];
            if (d >= lo && d < hi) {
                const int pos = atomicAdd(&cursor[d], 1);
                if (pos < CAP)
                    edges[(size_t)d * CAP + pos] =
                        ((unsigned)src[e] << 16) | (unsigned)f2bf(wm[e]);
            }
        }
        return;
    }

    // ---------------- GEMM1: h1[N,64] = x @ W1 + b1 (LDS-staged) ----------
    const int lane = t & 63;
    const int wv = t >> 6;
    const int nodeBase = ((int)blockIdx.x - sBlocks) * 64;

    f32x4 acc[4];
#pragma unroll
    for (int cg = 0; cg < 4; ++cg) acc[cg] = (f32x4){0.f, 0.f, 0.f, 0.f};

    for (int k0 = 0; k0 < D_IN; k0 += 64) {
#pragma unroll
        for (int hh = 0; hh < 2; ++hh) {
            const int g = t + hh * 256;          // 0..511
            const int row = g >> 3, slot = g & 7;
            int gn = nodeBase + row; if (gn >= N) gn = N - 1;
            const float* sp = x + (size_t)gn * D_IN + k0 + slot * 8;
            const float4 a = *reinterpret_cast<const float4*>(sp);
            const float4 b = *reinterpret_cast<const float4*>(sp + 4);
            uint4 p;
            p.x = (unsigned)f2bf(a.x) | ((unsigned)f2bf(a.y) << 16);
            p.y = (unsigned)f2bf(a.z) | ((unsigned)f2bf(a.w) << 16);
            p.z = (unsigned)f2bf(b.x) | ((unsigned)f2bf(b.y) << 16);
            p.w = (unsigned)f2bf(b.z) | ((unsigned)f2bf(b.w) << 16);
            *reinterpret_cast<uint4*>(lds + row * 128 + ((slot << 4) ^ ((row & 7) << 4))) = p;
        }
#pragma unroll
        for (int hh = 0; hh < 2; ++hh) {
            const int g = t + hh * 256;
            const int col = g >> 3, slot = g & 7;
            const uint4 p = *reinterpret_cast<const uint4*>(w1T + (size_t)col * D_IN + k0 + slot * 8);
            *reinterpret_cast<uint4*>(lds + 8192 + col * 128 + ((slot << 4) ^ ((col & 7) << 4))) = p;
        }
        __syncthreads();

        const int fr = lane & 15;
        const int fc = lane >> 4;
#pragma unroll
        for (int s = 0; s < 2; ++s) {
            const int slot = s * 4 + fc;
            const int arow = wv * 16 + fr;
            const bf16x8 afrag = *reinterpret_cast<const bf16x8*>(
                lds + arow * 128 + ((slot << 4) ^ ((arow & 7) << 4)));
#pragma unroll
            for (int cg = 0; cg < 4; ++cg) {
                const int brow = cg * 16 + fr;
                const bf16x8 bfrag = *reinterpret_cast<const bf16x8*>(
                    lds + 8192 + brow * 128 + ((slot << 4) ^ ((brow & 7) << 4)));
                acc[cg] = __builtin_amdgcn_mfma_f32_16x16x32_bf16(afrag, bfrag, acc[cg], 0, 0, 0);
            }
        }
        __syncthreads();
    }

    const int fr = lane & 15;
    const int rq = lane >> 4;
#pragma unroll
    for (int cg = 0; cg < 4; ++cg) {
        const int col = cg * 16 + fr;
        const float bb = b1[col];
#pragma unroll
        for (int r = 0; r < 4; ++r) {
            const int node = nodeBase + wv * 16 + rq * 4 + r;
            if (node < N)
                h1[(size_t)node * D_HID + col] = f2bf(acc[cg][r] + bb);
        }
    }
}

// ===========================================================================
// Aggregation 1 (64 ch): wave/node, lane=channel. XCD-aligned node mapping:
// slice = bid%8 so nodes aggregate on the XCD whose L2 holds their edge
// lines (scatter wrote slice s from blocks bid%8==s). 8-deep gathers,
// fused relu + bf16 store.
// ===========================================================================
__global__ __launch_bounds__(256)
void agg_hid(const unsigned short* __restrict__ h, const unsigned* __restrict__ edges,
             const int* __restrict__ count, unsigned short* __restrict__ agg1, int N) {
    const int lane = threadIdx.x & 63;
    const int wv   = (threadIdx.x >> 6);
    const int slice = (N + 7) >> 3;                       // 6250
    const int local = ((int)blockIdx.x >> 3) * 4 + wv;    // node within slice
    if (local >= slice) return;
    const int n = ((int)blockIdx.x & 7) * slice + local;
    if (n >= N) return;
    const unsigned er = edges[(size_t)n * CAP + lane];
    const int cnt = min(count[n], CAP);
    float acc = 0.f;
    int j = 0;
    for (; j + 8 <= cnt; j += 8) {
        unsigned p[8];
#pragma unroll
        for (int u = 0; u < 8; ++u) p[u] = (unsigned)__shfl((int)er, j + u);
        float v[8];
#pragma unroll
        for (int u = 0; u < 8; ++u) v[u] = bf2f(h[(size_t)(p[u] >> 16) * D_HID + lane]);
#pragma unroll
        for (int u = 0; u < 8; ++u)
            acc += bf2f((unsigned short)(p[u] & 0xffff)) * v[u];
    }
    for (; j < cnt; ++j) {
        const unsigned p0 = (unsigned)__shfl((int)er, j);
        acc += bf2f((unsigned short)(p0 & 0xffff)) *
               bf2f(h[(size_t)(p0 >> 16) * D_HID + lane]);
    }
    agg1[(size_t)n * D_HID + lane] = f2bf(fmaxf(acc, 0.f));  // fused relu
}

// ===========================================================================
// GEMM2 (MFMA bf16): h2[N,40](bf16) = agg1relu[N,64] @ W2 + b2
// ===========================================================================
__global__ __launch_bounds__(256)
void gemm2_mfma(const unsigned short* __restrict__ agg1,
                const unsigned short* __restrict__ w2T,
                const float* __restrict__ b2, unsigned short* __restrict__ h2, int N) {
    __shared__ unsigned char lds[8192 + 6144];  // A @0 (64x128B), B @8192 (48x128B)
    const int t = threadIdx.x;
    const int lane = t & 63;
    const int wv = t >> 6;
    const int nodeBase = blockIdx.x * 64;

#pragma unroll
    for (int hh = 0; hh < 2; ++hh) {
        const int g = t + hh * 256;
        const int row = g >> 3, slot = g & 7;
        int gn = nodeBase + row; if (gn >= N) gn = N - 1;
        const uint4 p = *reinterpret_cast<const uint4*>(agg1 + (size_t)gn * D_HID + slot * 8);
        *reinterpret_cast<uint4*>(lds + row * 128 + ((slot << 4) ^ ((row & 7) << 4))) = p;
    }
    for (int g = t; g < 384; g += 256) {
        const int row = g >> 3, slot = g & 7;
        const uint4 p = *reinterpret_cast<const uint4*>(w2T + (size_t)row * D_HID + slot * 8);
        *reinterpret_cast<uint4*>(lds + 8192 + row * 128 + ((slot << 4) ^ ((row & 7) << 4))) = p;
    }
    __syncthreads();

    f32x4 acc[3];
#pragma unroll
    for (int cg = 0; cg < 3; ++cg) acc[cg] = (f32x4){0.f, 0.f, 0.f, 0.f};

    const int fr = lane & 15;
    const int fc = lane >> 4;
#pragma unroll
    for (int s = 0; s < 2; ++s) {
        const int slot = s * 4 + fc;
        const int arow = wv * 16 + fr;
        const bf16x8 afrag = *reinterpret_cast<const bf16x8*>(
            lds + arow * 128 + ((slot << 4) ^ ((arow & 7) << 4)));
#pragma unroll
        for (int cg = 0; cg < 3; ++cg) {
            const int brow = cg * 16 + fr;
            const bf16x8 bfrag = *reinterpret_cast<const bf16x8*>(
                lds + 8192 + brow * 128 + ((slot << 4) ^ ((brow & 7) << 4)));
            acc[cg] = __builtin_amdgcn_mfma_f32_16x16x32_bf16(afrag, bfrag, acc[cg], 0, 0, 0);
        }
    }

    const int rq = lane >> 4;
#pragma unroll
    for (int cg = 0; cg < 3; ++cg) {
        const int col = cg * 16 + fr;
        if (col < D_OUT) {
            const float bb = b2[col];
#pragma unroll
            for (int r = 0; r < 4; ++r) {
                const int node = nodeBase + wv * 16 + rq * 4 + r;
                if (node < N)
                    h2[(size_t)node * D_OUT + col] = f2bf(acc[cg][r] + bb);
            }
        }
    }
}

// ===========================================================================
// Aggregation 2 (40 ch) + log_softmax. XCD-aligned node mapping, 8-deep.
// ===========================================================================
__global__ __launch_bounds__(256)
void agg40_lsm(const unsigned short* __restrict__ h2, const unsigned* __restrict__ edges,
               const int* __restrict__ count, float* __restrict__ out, int N) {
    const int lane = threadIdx.x & 63;
    const int col  = (lane < D_OUT) ? lane : 0;  // clamped gather, no branch
    const int wv   = (threadIdx.x >> 6);
    const int slice = (N + 7) >> 3;
    const int local = ((int)blockIdx.x >> 3) * 4 + wv;
    if (local >= slice) return;
    const int n = ((int)blockIdx.x & 7) * slice + local;
    if (n >= N) return;
    const unsigned er = edges[(size_t)n * CAP + lane];
    const int cnt = min(count[n], CAP);
    float acc = 0.f;
    int j = 0;
    for (; j + 8 <= cnt; j += 8) {
        unsigned p[8];
#pragma unroll
        for (int u = 0; u < 8; ++u) p[u] = (unsigned)__shfl((int)er, j + u);
        float v[8];
#pragma unroll
        for (int u = 0; u < 8; ++u) v[u] = bf2f(h2[(size_t)(p[u] >> 16) * D_OUT + col]);
#pragma unroll
        for (int u = 0; u < 8; ++u)
            acc += bf2f((unsigned short)(p[u] & 0xffff)) * v[u];
    }
    for (; j < cnt; ++j) {
        const unsigned p0 = (unsigned)__shfl((int)er, j);
        acc += bf2f((unsigned short)(p0 & 0xffff)) *
               bf2f(h2[(size_t)(p0 >> 16) * D_OUT + col]);
    }
    const float v = (lane < D_OUT) ? acc : -INFINITY;
    float m = v;
#pragma unroll
    for (int o = 32; o > 0; o >>= 1) m = fmaxf(m, __shfl_xor(m, o, 64));
    float s = (lane < D_OUT) ? __expf(v - m) : 0.f;
#pragma unroll
    for (int o = 32; o > 0; o >>= 1) s += __shfl_xor(s, o, 64);
    if (lane < D_OUT) out[(size_t)n * D_OUT + lane] = v - m - __logf(s);
}

// ===========================================================================
extern "C" void kernel_launch(void* const* d_in, const int* in_sizes, int n_in,
                              void* d_out, int out_size, void* d_ws, size_t ws_size,
                              hipStream_t stream) {
    const float* x   = (const float*)d_in[0];
    const int*   ei  = (const int*)d_in[1];
    const float* wm  = (const float*)d_in[2];
    const float* W1  = (const float*)d_in[3];
    const float* b1  = (const float*)d_in[4];
    const float* W2  = (const float*)d_in[5];
    const float* b2  = (const float*)d_in[6];

    const int N = in_sizes[0] / D_IN;   // 50000
    const int E = in_sizes[2];          // 800000
    const int* srcIdx = ei;
    const int* dstIdx = ei + E;

    // workspace layout (16B-aligned blocks)
    unsigned short* w1T    = (unsigned short*)d_ws;                   // 64 KiB
    unsigned short* h1bf   = w1T + (size_t)D_HID * D_IN;              // N*64 bf16
    unsigned short* agg1bf = h1bf + (size_t)N * D_HID;                // N*64 bf16 (relu'd)
    unsigned* edges        = (unsigned*)(agg1bf + (size_t)N * D_HID); // N*CAP u32
    int*   cursor          = (int*)(edges + (size_t)N * CAP);         // N (= counts)
    unsigned short* w2T    = (unsigned short*)(cursor + N);           // 48*64 bf16
    unsigned short* h2bf   = h1bf;                                    // reuse (h1 dead after agg_hid)
    float* out             = (float*)d_out;

    const int g1Blocks = (N + 63) / 64;          // 782
    const int sBlocks  = 1024;                   // 128 chunks x 8 XCD slices
    const int prepWork = N + D_IN * D_HID + 48 * D_HID;
    const int slice = (N + 7) >> 3;              // 6250
    const int aggBlocks = ((slice + 3) / 4) * 8; // XCD-aligned agg grid

    prep_all<<<(prepWork + 255) / 256, 256, 0, stream>>>(cursor, W1, w1T, W2, w2T, N);
    fat1<<<sBlocks + g1Blocks, 256, 0, stream>>>(
        x, w1T, b1, h1bf, srcIdx, dstIdx, wm, cursor, edges, E, N, sBlocks);
    agg_hid<<<aggBlocks, 256, 0, stream>>>(h1bf, edges, cursor, agg1bf, N);
    gemm2_mfma<<<g1Blocks, 256, 0, stream>>>(agg1bf, w2T, b2, h2bf, N);
    agg40_lsm<<<aggBlocks, 256, 0, stream>>>(h2bf, edges, cursor, out, N);
}